// Round 8
// baseline (296.345 us; speedup 1.0000x reference)
//
#include <hip/hip_runtime.h>

// MultiResolutionHashEncoding, level-phased via separate launches (hard
// device-wide barrier per level => one 4 MiB slice active per XCD L2).
// Parity trick: PRIMES[0]==1 => for even ux, corners (0,iy,iz),(1,iy,iz) sit
// at table slots {2k,2k+1} -> one aligned float4 load covers both (avg 6
// gather requests/point-level instead of 8; kernel is MSHR-latency bound at
// ~0.33 lines/cy/CU).
// R8: write out[p*16+l] DIRECTLY from each level kernel (8B @ 128B stride).
// Stores don't allocate L1 MSHRs -> near-free in a gather-bound kernel;
// eliminates the 64 MiB ws + 25 us transpose dispatch entirely.
//
// Scalings floor(16*growth^l) with f32 semantics of the reference
// (growth rounds DOWN in f32 => level 15 scaling is 2047, not 2048).
__device__ __constant__ float c_scal[16] = {
    16.f, 22.f, 30.f, 42.f, 58.f, 80.f, 111.f, 153.f,
    212.f, 294.f, 406.f, 561.f, 776.f, 1072.f, 1482.f, 2047.f
};

#define TBL_T 524288u   // 2^19 entries per level
#define NPTS  524288u
#define TMASK (TBL_T - 1u)

// Compute one level's feature for one point. Parity-split gather.
__device__ __forceinline__ float2 level_feat(
        const float2* __restrict__ tbl, float px, float py, float pz,
        float s, unsigned base) {
    float sx = px * s, sy = py * s, sz = pz * s;
    float cx = floorf(sx), cy = floorf(sy), cz = floorf(sz);
    float fx = sx - cx, fy = sy - cy, fz = sz - cz;

    unsigned ux = (unsigned)cx, uy = (unsigned)cy, uz = (unsigned)cz;

    unsigned hy0 = uy * 2654435761u, hy1 = (uy + 1u) * 2654435761u;
    unsigned hz0 = uz * 805459861u,  hz1 = (uz + 1u) * 805459861u;

    float wx1 = fx, wx0 = 1.f - fx;
    float wy1 = fy, wy0 = 1.f - fy;
    float wz1 = fz, wz0 = 1.f - fz;

    // per-(iy,iz) combined weights; j = (iy<<1)|iz
    float wyz[4] = { wy0 * wz0, wy0 * wz1, wy1 * wz0, wy1 * wz1 };
    unsigned hyz[4] = { hy0 ^ hz0, hy0 ^ hz1, hy1 ^ hz0, hy1 ^ hz1 };

    float o0 = 0.f, o1 = 0.f;

    if ((ux & 1u) == 0u) {
        // even ux: corners (0,iy,iz) and (1,iy,iz) at slots {2k,2k+1}
        float4 f[4];
#pragma unroll
        for (int j = 0; j < 4; ++j) {
            unsigned idx0 = ((ux ^ hyz[j]) & TMASK) + base;   // ix=0 slot
            f[j] = *reinterpret_cast<const float4*>(
                       reinterpret_cast<const float*>(tbl) + ((idx0 & ~1u) << 1));
        }
#pragma unroll
        for (int j = 0; j < 4; ++j) {
            unsigned idx0 = ((ux ^ hyz[j]) & TMASK) + base;
            bool hi0 = (idx0 & 1u) != 0u;   // ix=0 in hi half?
            float c0x = hi0 ? f[j].z : f[j].x;
            float c0y = hi0 ? f[j].w : f[j].y;
            float c1x = hi0 ? f[j].x : f[j].z;
            float c1y = hi0 ? f[j].y : f[j].w;
            o0 += c0x * (wx0 * wyz[j]) + c1x * (wx1 * wyz[j]);
            o1 += c0y * (wx0 * wyz[j]) + c1y * (wx1 * wyz[j]);
        }
    } else {
        // odd ux: slots unrelated, 8 separate float2 gathers
        unsigned ux1 = ux + 1u;
        float2 v0[4], v1[4];
#pragma unroll
        for (int j = 0; j < 4; ++j) {
            v0[j] = tbl[((ux  ^ hyz[j]) & TMASK) + base];
            v1[j] = tbl[((ux1 ^ hyz[j]) & TMASK) + base];
        }
#pragma unroll
        for (int j = 0; j < 4; ++j) {
            o0 += v0[j].x * (wx0 * wyz[j]) + v1[j].x * (wx1 * wyz[j]);
            o1 += v0[j].y * (wx0 * wyz[j]) + v1[j].y * (wx1 * wyz[j]);
        }
    }
    return make_float2(o0, o1);
}

// One fine level per launch; write out[p][l] directly.
__global__ __launch_bounds__(256) void hashenc_level(
        const float* __restrict__ x,
        const float2* __restrict__ tbl,
        float2* __restrict__ out,
        int l) {
    unsigned p = blockIdx.x * 256u + threadIdx.x;
    float px = x[p * 3 + 0], py = x[p * 3 + 1], pz = x[p * 3 + 2];
    out[(size_t)p * 16u + (unsigned)l] =
        level_feat(tbl, px, py, pz, c_scal[l], (unsigned)l * TBL_T);
}

// Levels 0..4 fused (combined slice footprint ~2.6 MB); direct writes.
__global__ __launch_bounds__(256) void hashenc_coarse(
        const float* __restrict__ x,
        const float2* __restrict__ tbl,
        float2* __restrict__ out) {
    unsigned p = blockIdx.x * 256u + threadIdx.x;
    float px = x[p * 3 + 0], py = x[p * 3 + 1], pz = x[p * 3 + 2];
    float2* dst = out + (size_t)p * 16u;
#pragma unroll
    for (int l = 0; l < 5; ++l)
        dst[l] = level_feat(tbl, px, py, pz, c_scal[l], (unsigned)l * TBL_T);
}

extern "C" void kernel_launch(void* const* d_in, const int* in_sizes, int n_in,
                              void* d_out, int out_size, void* d_ws, size_t ws_size,
                              hipStream_t stream) {
    const float*  x   = (const float*)d_in[0];
    const float2* tbl = (const float2*)d_in[1];   // [L*T][F=2] floats
    float2*       out = (float2*)d_out;           // [NPTS][16] float2

    const unsigned block = 256u;
    const unsigned grid  = NPTS / block;          // 2048 blocks

    hashenc_coarse<<<grid, block, 0, stream>>>(x, tbl, out);
    for (int l = 5; l < 16; ++l)
        hashenc_level<<<grid, block, 0, stream>>>(x, tbl, out, l);
}

// Round 9
// 244.492 us; speedup vs baseline: 1.2121x; 1.2121x over previous
//
#include <hip/hip_runtime.h>

// MultiResolutionHashEncoding, level-phased via separate launches (hard
// device-wide barrier per level => one 4 MiB slice active per XCD L2).
// Parity trick: PRIMES[0]==1 => for even ux, corners (0,iy,iz),(1,iy,iz) sit
// at table slots {2k,2k+1} -> one aligned float4 load covers both (avg 6
// gather lines/point-level instead of 8; kernel is random-gather bound at
// ~0.33 lines/cy/CU).
// R9: transpose FUSED into the level-15 dispatch (reads ws[0..14] coalesced,
// keeps its own feature in registers, writes 128 B/point contiguous).
// R8 lesson: partial-line strided stores cause L2 write-allocate RMW +
// slice eviction — only full-line writes are acceptable.
//
// Scalings floor(16*growth^l) with f32 semantics of the reference
// (growth rounds DOWN in f32 => level 15 scaling is 2047, not 2048).
__device__ __constant__ float c_scal[16] = {
    16.f, 22.f, 30.f, 42.f, 58.f, 80.f, 111.f, 153.f,
    212.f, 294.f, 406.f, 561.f, 776.f, 1072.f, 1482.f, 2047.f
};

#define TBL_T 524288u   // 2^19 entries per level
#define NPTS  524288u
#define TMASK (TBL_T - 1u)

// Compute one level's feature for one point. Parity-split gather.
__device__ __forceinline__ float2 level_feat(
        const float2* __restrict__ tbl, float px, float py, float pz,
        float s, unsigned base) {
    float sx = px * s, sy = py * s, sz = pz * s;
    float cx = floorf(sx), cy = floorf(sy), cz = floorf(sz);
    float fx = sx - cx, fy = sy - cy, fz = sz - cz;

    unsigned ux = (unsigned)cx, uy = (unsigned)cy, uz = (unsigned)cz;

    unsigned hy0 = uy * 2654435761u, hy1 = (uy + 1u) * 2654435761u;
    unsigned hz0 = uz * 805459861u,  hz1 = (uz + 1u) * 805459861u;

    float wx1 = fx, wx0 = 1.f - fx;
    float wy1 = fy, wy0 = 1.f - fy;
    float wz1 = fz, wz0 = 1.f - fz;

    // per-(iy,iz) combined weights; j = (iy<<1)|iz
    float wyz[4] = { wy0 * wz0, wy0 * wz1, wy1 * wz0, wy1 * wz1 };
    unsigned hyz[4] = { hy0 ^ hz0, hy0 ^ hz1, hy1 ^ hz0, hy1 ^ hz1 };

    float o0 = 0.f, o1 = 0.f;

    if ((ux & 1u) == 0u) {
        // even ux: corners (0,iy,iz) and (1,iy,iz) at slots {2k,2k+1}
        float4 f[4];
#pragma unroll
        for (int j = 0; j < 4; ++j) {
            unsigned idx0 = ((ux ^ hyz[j]) & TMASK) + base;   // ix=0 slot
            f[j] = *reinterpret_cast<const float4*>(
                       reinterpret_cast<const float*>(tbl) + ((idx0 & ~1u) << 1));
        }
#pragma unroll
        for (int j = 0; j < 4; ++j) {
            unsigned idx0 = ((ux ^ hyz[j]) & TMASK) + base;
            bool hi0 = (idx0 & 1u) != 0u;   // ix=0 in hi half?
            float c0x = hi0 ? f[j].z : f[j].x;
            float c0y = hi0 ? f[j].w : f[j].y;
            float c1x = hi0 ? f[j].x : f[j].z;
            float c1y = hi0 ? f[j].y : f[j].w;
            o0 += c0x * (wx0 * wyz[j]) + c1x * (wx1 * wyz[j]);
            o1 += c0y * (wx0 * wyz[j]) + c1y * (wx1 * wyz[j]);
        }
    } else {
        // odd ux: slots unrelated, 8 separate float2 gathers
        unsigned ux1 = ux + 1u;
        float2 v0[4], v1[4];
#pragma unroll
        for (int j = 0; j < 4; ++j) {
            v0[j] = tbl[((ux  ^ hyz[j]) & TMASK) + base];
            v1[j] = tbl[((ux1 ^ hyz[j]) & TMASK) + base];
        }
#pragma unroll
        for (int j = 0; j < 4; ++j) {
            o0 += v0[j].x * (wx0 * wyz[j]) + v1[j].x * (wx1 * wyz[j]);
            o1 += v0[j].y * (wx0 * wyz[j]) + v1[j].y * (wx1 * wyz[j]);
        }
    }
    return make_float2(o0, o1);
}

// One fine level per launch (levels 5..14); writes its ws slab.
__global__ __launch_bounds__(256) void hashenc_level(
        const float* __restrict__ x,
        const float2* __restrict__ tbl,
        float2* __restrict__ ws,
        int l) {
    unsigned p = blockIdx.x * 256u + threadIdx.x;
    float px = x[p * 3 + 0], py = x[p * 3 + 1], pz = x[p * 3 + 2];
    ws[(size_t)l * NPTS + p] =
        level_feat(tbl, px, py, pz, c_scal[l], (unsigned)l * TBL_T);
}

// Levels 0..4 fused (combined slice footprint ~2.6 MB).
__global__ __launch_bounds__(256) void hashenc_coarse(
        const float* __restrict__ x,
        const float2* __restrict__ tbl,
        float2* __restrict__ ws) {
    unsigned p = blockIdx.x * 256u + threadIdx.x;
    float px = x[p * 3 + 0], py = x[p * 3 + 1], pz = x[p * 3 + 2];
#pragma unroll
    for (int l = 0; l < 5; ++l)
        ws[(size_t)l * NPTS + p] =
            level_feat(tbl, px, py, pz, c_scal[l], (unsigned)l * TBL_T);
}

// Level 15 + transpose fused: compute own feature in registers, read the 15
// completed slabs (coalesced), write 128 B/point contiguous final output.
__global__ __launch_bounds__(256) void hashenc_last(
        const float* __restrict__ x,
        const float2* __restrict__ tbl,
        const float2* __restrict__ ws,
        float4* __restrict__ out) {
    unsigned p = blockIdx.x * 256u + threadIdx.x;
    float px = x[p * 3 + 0], py = x[p * 3 + 1], pz = x[p * 3 + 2];

    // own gathers first (latency overlapped with slab reads below)
    float2 f15 = level_feat(tbl, px, py, pz, c_scal[15], 15u * TBL_T);

    float2 v[15];
#pragma unroll
    for (int l = 0; l < 15; ++l) v[l] = ws[(size_t)l * NPTS + p];

    float4* dst = out + (size_t)p * 8u;
#pragma unroll
    for (int q = 0; q < 7; ++q)
        dst[q] = make_float4(v[2 * q].x, v[2 * q].y, v[2 * q + 1].x, v[2 * q + 1].y);
    dst[7] = make_float4(v[14].x, v[14].y, f15.x, f15.y);
}

// Fallback (ws too small): single kernel, one thread per point.
__global__ __launch_bounds__(256) void hashenc_mono(
        const float* __restrict__ x,
        const float2* __restrict__ tbl,
        float4* __restrict__ out) {
    unsigned p = blockIdx.x * 256u + threadIdx.x;
    float px = x[p * 3 + 0], py = x[p * 3 + 1], pz = x[p * 3 + 2];
    float o[32];
#pragma unroll
    for (int l = 0; l < 16; ++l) {
        float2 f = level_feat(tbl, px, py, pz, c_scal[l], (unsigned)l * TBL_T);
        o[2 * l] = f.x; o[2 * l + 1] = f.y;
        __syncthreads();
    }
    float4* dst = out + (size_t)p * 8u;
#pragma unroll
    for (int q = 0; q < 8; ++q)
        dst[q] = make_float4(o[4 * q], o[4 * q + 1], o[4 * q + 2], o[4 * q + 3]);
}

extern "C" void kernel_launch(void* const* d_in, const int* in_sizes, int n_in,
                              void* d_out, int out_size, void* d_ws, size_t ws_size,
                              hipStream_t stream) {
    const float*  x   = (const float*)d_in[0];
    const float2* tbl = (const float2*)d_in[1];   // [L*T][F=2] floats
    const size_t need = (size_t)15 * NPTS * sizeof(float2);  // 60 MiB

    const unsigned block = 256u;
    const unsigned grid  = NPTS / block;          // 2048 blocks

    if (ws_size >= need) {
        float2* ws = (float2*)d_ws;
        hashenc_coarse<<<grid, block, 0, stream>>>(x, tbl, ws);
        for (int l = 5; l < 15; ++l)
            hashenc_level<<<grid, block, 0, stream>>>(x, tbl, ws, l);
        hashenc_last<<<grid, block, 0, stream>>>(x, tbl, ws, (float4*)d_out);
    } else {
        hashenc_mono<<<grid, block, 0, stream>>>(x, tbl, (float4*)d_out);
    }
}